// Round 13
// baseline (289.046 us; speedup 1.0000x reference)
//
#include <hip/hip_runtime.h>
#include <hip/hip_bf16.h>
#include <cstdint>

typedef __attribute__((ext_vector_type(8))) short v8s;   // 8 x bf16 (4 VGPR) MFMA frag
typedef __attribute__((ext_vector_type(4))) float v4f;   // MFMA accum

__device__ __forceinline__ unsigned short f32_to_bf16(float f) {
  unsigned int u = __builtin_bit_cast(unsigned int, f);
  u += 0x7fffu + ((u >> 16) & 1u);           // RNE
  return (unsigned short)(u >> 16);
}
__device__ __forceinline__ float bf16_to_f32(unsigned short u) {
  return __builtin_bit_cast(float, (unsigned int)u << 16);
}

__device__ __forceinline__ void gload_lds16(const void* g, void* l) {
  __builtin_amdgcn_global_load_lds((const __attribute__((address_space(1))) void*)g,
                                   (__attribute__((address_space(3))) void*)l, 16, 0, 0);
}

enum { EPI_QKV = 0, EPI_BF16 = 1, EPI_F32_BIAS = 2, EPI_BF16_SCALE = 3 };

// ---------------------------------------------------------------------------
// 128x128 NT GEMM. Two B-operand paths:
//  REGB=0: round-12 proven path — both A and B staged via global_load_lds w16
//          (pre-swizzled source), frag ds_read_b128 conflict-free.
//  REGB=1: B read DIRECTLY from global into VGPRs (use when B is an L2-resident
//          weight matrix: Wc_t 6MB / Wp_t 2MB). Value-identical to the LDS path
//          (swizzles cancel: bf[f][j] = Bg[wn*64+f*16+l15][k0+kk*32+l4q*8+j]).
//          Halves LDS traffic + staging count; B-load latency shares the same
//          __syncthreads drain as A staging. LDS 16KB/block.
// Epilogues:
//   EPI_QKV:  tileN<1024 -> Q dense; <2048 -> K dense; >=2048 -> V^T (ushort4).
//   EPI_BF16: C = bf16(acc) (PV) | EPI_F32_BIAS (out) | EPI_BF16_SCALE (scores)
// ---------------------------------------------------------------------------
template <int MODE, int REGB>
__global__ __launch_bounds__(256)
void gemm_nt(const unsigned short* __restrict__ A, long long strideA, int lda,
             const unsigned short* __restrict__ B, long long strideB, int ldb,
             void* __restrict__ Cout, long long strideC, int ldc,
             const float* __restrict__ bias,
             float scale, int K,
             unsigned short* __restrict__ qb,
             unsigned short* __restrict__ kb,
             unsigned short* __restrict__ vt)
{
  __shared__ __attribute__((aligned(16))) short smA[128 * 64];
  __shared__ __attribute__((aligned(16))) short smB[REGB ? 8 : 128 * 64];

  const int tid  = threadIdx.x;
  const int lane = tid & 63;
  const int wave = tid >> 6;
  const int wm = wave >> 1, wn = wave & 1;
  const int bz = blockIdx.z;
  const int tileM = blockIdx.y * 128, tileN = blockIdx.x * 128;

  const unsigned short* Ag = A + (long long)bz * strideA + (long long)tileM * lda;
  const unsigned short* Bg = B + (long long)bz * strideB + (long long)tileN * ldb;

  const int l8    = lane >> 3;
  const int srcCb = (lane & 7) ^ l8;
  const int l15   = lane & 15, l4q = lane >> 4;

  // ---- A staging pointers (advance by 64 elems per K-iter) ----
  const unsigned short* ga[4];
  void* la[4];
  #pragma unroll
  for (int i = 0; i < 4; ++i) {
    const int c   = wave * 4 + i;
    const int row = c * 8 + l8;
    ga[i] = Ag + (long long)row * lda + srcCb * 8;
    la[i] = &smA[c * 512];
  }

  // ---- A frag-read bases (K-invariant; reads use +f*1024 elems) ----
  const int sxor = l15 & 7;
  const short* baseA[2];
  #pragma unroll
  for (int kk = 0; kk < 2; ++kk)
    baseA[kk] = &smA[(wm * 64 + l15) * 64 + ((kk * 4 + l4q) ^ sxor) * 8];

  // ---- B path setup ----
  const unsigned short* gb[4];   // REGB=0: staging ptrs
  void* lb[4];
  const short* baseB[2];
  const unsigned short* pB[2][4];  // REGB=1: direct frag ptrs
  if constexpr (!REGB) {
    #pragma unroll
    for (int i = 0; i < 4; ++i) {
      const int c   = wave * 4 + i;
      const int row = c * 8 + l8;
      gb[i] = Bg + (long long)row * ldb + srcCb * 8;
      lb[i] = &smB[c * 512];
    }
    #pragma unroll
    for (int kk = 0; kk < 2; ++kk)
      baseB[kk] = &smB[(wn * 64 + l15) * 64 + ((kk * 4 + l4q) ^ sxor) * 8];
  } else {
    #pragma unroll
    for (int kk = 0; kk < 2; ++kk)
      #pragma unroll
      for (int f = 0; f < 4; ++f)
        pB[kk][f] = Bg + (long long)(wn * 64 + f * 16 + l15) * ldb + kk * 32 + l4q * 8;
  }

  v4f acc[4][4] = {};

  for (int it = K >> 6; it > 0; --it) {
    v8s bfr[2][4];
    if constexpr (REGB) {
      #pragma unroll
      for (int kk = 0; kk < 2; ++kk)
        #pragma unroll
        for (int f = 0; f < 4; ++f) {
          bfr[kk][f] = *(const v8s*)pB[kk][f];
          pB[kk][f] += 64;
        }
    }
    #pragma unroll
    for (int i = 0; i < 4; ++i) {
      gload_lds16(ga[i], la[i]);
      ga[i] += 64;
      if constexpr (!REGB) {
        gload_lds16(gb[i], lb[i]);
        gb[i] += 64;
      }
    }
    __syncthreads();   // drains A staging (and, for REGB, the B reg-loads)
    #pragma unroll
    for (int kk = 0; kk < 2; ++kk) {
      v8s af[4], bf[4];
      #pragma unroll
      for (int f = 0; f < 4; ++f) {
        af[f] = *(const v8s*)(baseA[kk] + f * 1024);
        if constexpr (!REGB) bf[f] = *(const v8s*)(baseB[kk] + f * 1024);
        else                 bf[f] = bfr[kk][f];
      }
      #pragma unroll
      for (int fm = 0; fm < 4; ++fm)
        #pragma unroll
        for (int fn = 0; fn < 4; ++fn)
          acc[fm][fn] = __builtin_amdgcn_mfma_f32_16x16x32_bf16(af[fm], bf[fn], acc[fm][fn], 0, 0, 0);
    }
    __syncthreads();
  }

  // ---- epilogue: C/D layout col=lane&15, row=(lane>>4)*4+reg ----
  const int row0 = tileM + wm * 64 + (lane >> 4) * 4;
  const int col0 = tileN + wn * 64 + l15;

  #pragma unroll
  for (int fm = 0; fm < 4; ++fm) {
    #pragma unroll
    for (int fn = 0; fn < 4; ++fn) {
      const int col = col0 + fn * 16;
      if (MODE == EPI_QKV) {
        const float bb = bias[col];
        if (tileN >= 2048) {
          // V^T: d=col-2048, batch=row>>11, s=row&2047 (4 consecutive)
          const int rowb = row0 + fm * 16;
          const int d = col - 2048;
          const int b = rowb >> 11;
          const int s0 = rowb & 2047;
          ushort4 w;
          w.x = f32_to_bf16(acc[fm][fn][0] + bb);
          w.y = f32_to_bf16(acc[fm][fn][1] + bb);
          w.z = f32_to_bf16(acc[fm][fn][2] + bb);
          w.w = f32_to_bf16(acc[fm][fn][3] + bb);
          *(ushort4*)&vt[((long long)b * 1024 + d) * 2048 + s0] = w;
        } else {
          unsigned short* dst = (tileN < 1024) ? qb : kb;
          const int colr = col & 1023;
          #pragma unroll
          for (int r = 0; r < 4; ++r) {
            const int row = row0 + fm * 16 + r;
            dst[(long long)row * 1024 + colr] = f32_to_bf16(acc[fm][fn][r] + bb);
          }
        }
      } else {
        #pragma unroll
        for (int r = 0; r < 4; ++r) {
          const int row = row0 + fm * 16 + r;
          const float v = acc[fm][fn][r];
          if (MODE == EPI_BF16_SCALE) {
            unsigned short* C = (unsigned short*)Cout + (long long)bz * strideC;
            C[(long long)row * ldc + col] = f32_to_bf16(v * scale);
          } else if (MODE == EPI_F32_BIAS) {
            float* C = (float*)Cout + (long long)bz * strideC;
            C[(long long)row * ldc + col] = v + bias[col];
          } else {
            unsigned short* C = (unsigned short*)Cout + (long long)bz * strideC;
            C[(long long)row * ldc + col] = f32_to_bf16(v);
          }
        }
      }
    }
  }
}

// ---------------------------------------------------------------------------
__global__ __launch_bounds__(256)
void cvt_f32_bf16_kernel(const float* __restrict__ in, unsigned short* __restrict__ out,
                         long long n)
{
  const long long i = ((long long)blockIdx.x * 256 + threadIdx.x) * 4;
  if (i >= n) return;
  const float4 v = *(const float4*)(in + i);
  typedef __attribute__((ext_vector_type(4))) unsigned short v4us;
  v4us o;
  o.x = f32_to_bf16(v.x); o.y = f32_to_bf16(v.y);
  o.z = f32_to_bf16(v.z); o.w = f32_to_bf16(v.w);
  *(v4us*)(out + i) = o;
}

__global__ __launch_bounds__(256)
void transpose_f32_bf16_kernel(const float* __restrict__ in, unsigned short* __restrict__ out,
                               int R, int C)   // in [R][C] f32 -> out [C][R] bf16
{
  __shared__ float t[32][33];
  const int c0 = blockIdx.x * 32, r0 = blockIdx.y * 32;
  const int tx = threadIdx.x, ty = threadIdx.y;
  for (int i = ty; i < 32; i += 8)
    t[i][tx] = in[(long long)(r0 + i) * C + (c0 + tx)];
  __syncthreads();
  for (int i = ty; i < 32; i += 8)
    out[(long long)(c0 + i) * R + (r0 + tx)] = f32_to_bf16(t[tx][i]);
}

// one WAVE per row: probs = softmax(bf16_scores + sw_f32). 4 rows/block,
// pure shuffle reduction, vectorized sw (float4) and score (v8s) loads.
__global__ __launch_bounds__(256)
void softmax_rows_bf16(const unsigned short* __restrict__ scores,
                       const float* __restrict__ sw,
                       unsigned short* __restrict__ probs)
{
  const int wid  = threadIdx.x >> 6;
  const int lane = threadIdx.x & 63;
  const long long row = (long long)blockIdx.x * 4 + wid;
  const unsigned short* src = scores + row * 2048;
  const float* swr = sw + row * 2048;
  unsigned short* dst = probs + row * 2048;

  float v[32];
  #pragma unroll
  for (int c = 0; c < 4; ++c) {
    const v8s in = *(const v8s*)(src + c * 512 + lane * 8);
    const float4 s0 = *(const float4*)(swr + c * 512 + lane * 8);
    const float4 s1 = *(const float4*)(swr + c * 512 + lane * 8 + 4);
    v[c * 8 + 0] = bf16_to_f32((unsigned short)in[0]) + s0.x;
    v[c * 8 + 1] = bf16_to_f32((unsigned short)in[1]) + s0.y;
    v[c * 8 + 2] = bf16_to_f32((unsigned short)in[2]) + s0.z;
    v[c * 8 + 3] = bf16_to_f32((unsigned short)in[3]) + s0.w;
    v[c * 8 + 4] = bf16_to_f32((unsigned short)in[4]) + s1.x;
    v[c * 8 + 5] = bf16_to_f32((unsigned short)in[5]) + s1.y;
    v[c * 8 + 6] = bf16_to_f32((unsigned short)in[6]) + s1.z;
    v[c * 8 + 7] = bf16_to_f32((unsigned short)in[7]) + s1.w;
  }

  float m = v[0];
  #pragma unroll
  for (int j = 1; j < 32; ++j) m = fmaxf(m, v[j]);
  #pragma unroll
  for (int o = 32; o; o >>= 1) m = fmaxf(m, __shfl_xor(m, o));

  float s = 0.f;
  #pragma unroll
  for (int j = 0; j < 32; ++j) { v[j] = __expf(v[j] - m); s += v[j]; }
  #pragma unroll
  for (int o = 32; o; o >>= 1) s += __shfl_xor(s, o);
  const float inv = 1.0f / s;

  #pragma unroll
  for (int c = 0; c < 4; ++c) {
    v8s o8;
    #pragma unroll
    for (int j = 0; j < 8; ++j) o8[j] = (short)f32_to_bf16(v[c * 8 + j] * inv);
    *(v8s*)(dst + c * 512 + lane * 8) = o8;
  }
}

// ---------------------------------------------------------------------------
extern "C" void kernel_launch(void* const* d_in, const int* in_sizes, int n_in,
                              void* d_out, int out_size, void* d_ws, size_t ws_size,
                              hipStream_t stream) {
  (void)in_sizes; (void)n_in; (void)out_size; (void)ws_size;
  const float* x   = (const float*)d_in[0];
  const float* sw  = (const float*)d_in[1];
  const float* W_c = (const float*)d_in[2];
  const float* b_c = (const float*)d_in[3];
  const float* W_p = (const float*)d_in[4];
  const float* b_p = (const float*)d_in[5];
  float* out = (float*)d_out;

  const int Bb = 4, S = 2048, H = 1024, Ha = 1024, P = 1024;
  const int M = Bb * S;                              // 8192
  char* ws = (char*)d_ws;
  const long long MB = 1024LL * 1024LL;
  // ws layout (120 MB), time-sliced overlap in [0,32MB):
  //   x_bf [0,16) steps 1-4 | scores [0,32) steps 5-6 | ctx [0,16) steps 7-8
  unsigned short* scores = (unsigned short*)(ws + 0);         // 32 MB bf16 [B*S][S]
  unsigned short* x_bf   = (unsigned short*)(ws + 0);         // 16 MB
  unsigned short* ctx    = (unsigned short*)(ws + 0);         // 16 MB
  unsigned short* probs  = (unsigned short*)(ws + 32 * MB);   // 32 MB
  unsigned short* qbuf   = (unsigned short*)(ws + 64 * MB);   // 16 MB [8192][1024]
  unsigned short* kbuf   = (unsigned short*)(ws + 80 * MB);   // 16 MB [8192][1024]
  unsigned short* Vt     = (unsigned short*)(ws + 96 * MB);   // 16 MB [4][1024][2048]
  unsigned short* Wc_t   = (unsigned short*)(ws + 112 * MB);  // 6 MB  [3072][1024]
  unsigned short* Wp_t   = (unsigned short*)(ws + 118 * MB);  // 2 MB  [1024][1024]

  const dim3 tb(32, 8);

  // 1) x -> bf16
  cvt_f32_bf16_kernel<<<(unsigned)((long long)M * H / 4 / 256), 256, 0, stream>>>(
      x, x_bf, (long long)M * H);
  // 2,3) W_c^T, W_p^T (f32 -> bf16)
  transpose_f32_bf16_kernel<<<dim3(3 * Ha / 32, H / 32), tb, 0, stream>>>(W_c, Wc_t, H, 3 * Ha);
  transpose_f32_bf16_kernel<<<dim3(P / 32, Ha / 32), tb, 0, stream>>>(W_p, Wp_t, Ha, P);
  // 4) QKV (REGB: W_c^T L2-resident): Q dense, K dense, V^T, all +b_c
  gemm_nt<EPI_QKV, 1><<<dim3(3 * Ha / 128, M / 128, 1), 256, 0, stream>>>(
      x_bf, 0, H, Wc_t, 0, H, nullptr, 0, 0, b_c, 0.f, H, qbuf, kbuf, Vt);
  // 5) scores = bf16((Q @ K^T) * rsqrt(1024))   (+sw deferred to softmax)
  gemm_nt<EPI_BF16_SCALE, 0><<<dim3(S / 128, S / 128, Bb), 256, 0, stream>>>(
      qbuf, (long long)S * Ha, Ha, kbuf, (long long)S * Ha, Ha,
      scores, (long long)S * S, S, nullptr, 0.03125f, Ha,
      nullptr, nullptr, nullptr);
  // 6) probs = softmax(scores + sw)  (wave per row)
  softmax_rows_bf16<<<Bb * S / 4, 256, 0, stream>>>(scores, sw, probs);
  // 7) ctx = probs @ V   (bf16 out)
  gemm_nt<EPI_BF16, 0><<<dim3(Ha / 128, S / 128, Bb), 256, 0, stream>>>(
      probs, (long long)S * S, S, Vt, (long long)Ha * S, S,
      ctx, (long long)S * Ha, Ha, nullptr, 0.f, S,
      nullptr, nullptr, nullptr);
  // 8) out = ctx @ W_p + b_p   (REGB: W_p^T L2-resident, fp32 out)
  gemm_nt<EPI_F32_BIAS, 1><<<dim3(P / 128, M / 128, 1), 256, 0, stream>>>(
      ctx, 0, Ha, Wp_t, 0, Ha, out, 0, P, b_p, 0.f, Ha,
      nullptr, nullptr, nullptr);
}

// Round 14
// 226.483 us; speedup vs baseline: 1.2762x; 1.2762x over previous
//
#include <hip/hip_runtime.h>
#include <hip/hip_bf16.h>
#include <cstdint>

typedef __attribute__((ext_vector_type(8))) short v8s;   // 8 x bf16 (4 VGPR) MFMA frag
typedef __attribute__((ext_vector_type(4))) float v4f;   // MFMA accum

__device__ __forceinline__ unsigned short f32_to_bf16(float f) {
  unsigned int u = __builtin_bit_cast(unsigned int, f);
  u += 0x7fffu + ((u >> 16) & 1u);           // RNE
  return (unsigned short)(u >> 16);
}
__device__ __forceinline__ float bf16_to_f32(unsigned short u) {
  return __builtin_bit_cast(float, (unsigned int)u << 16);
}

__device__ __forceinline__ void gload_lds16(const void* g, void* l) {
  __builtin_amdgcn_global_load_lds((const __attribute__((address_space(1))) void*)g,
                                   (__attribute__((address_space(3))) void*)l, 16, 0, 0);
}

enum { EPI_QKV = 0, EPI_BF16 = 1, EPI_F32_BIAS = 2, EPI_BF16_SCALE = 3 };

// ---------------------------------------------------------------------------
// 128x128 NT GEMM — round-12 proven optimum (226.85 µs pipeline total):
// single 32 KiB LDS buffer, global_load_lds w16 with pre-swizzled source,
// 16x16x32 frags with precomputed K-invariant read bases (XOR swizzle term is
// f-independent since row&7 == l15&7), 0 bank conflicts, 2 barriers/K-tile,
// no block swizzle (round-8 A/B: harmful), no REGB (round-13 A/B: gather
// pattern 64x transaction blowup, harmful).
// Epilogues:
//   EPI_QKV:  tileN<1024 -> Q dense; <2048 -> K dense; >=2048 -> V^T (ushort4).
//   EPI_BF16: C = bf16(acc) (PV) | EPI_F32_BIAS (out) | EPI_BF16_SCALE (scores)
// ---------------------------------------------------------------------------
template <int MODE>
__global__ __launch_bounds__(256)
void gemm_nt(const unsigned short* __restrict__ A, long long strideA, int lda,
             const unsigned short* __restrict__ B, long long strideB, int ldb,
             void* __restrict__ Cout, long long strideC, int ldc,
             const float* __restrict__ bias,
             float scale, int K,
             unsigned short* __restrict__ qb,
             unsigned short* __restrict__ kb,
             unsigned short* __restrict__ vt)
{
  __shared__ __attribute__((aligned(16))) short smA[128 * 64];
  __shared__ __attribute__((aligned(16))) short smB[128 * 64];

  const int tid  = threadIdx.x;
  const int lane = tid & 63;
  const int wave = tid >> 6;
  const int wm = wave >> 1, wn = wave & 1;
  const int bz = blockIdx.z;
  const int tileM = blockIdx.y * 128, tileN = blockIdx.x * 128;

  const unsigned short* Ag = A + (long long)bz * strideA + (long long)tileM * lda;
  const unsigned short* Bg = B + (long long)bz * strideB + (long long)tileN * ldb;

  const int l8    = lane >> 3;
  const int srcCb = (lane & 7) ^ l8;
  const int l15   = lane & 15, l4q = lane >> 4;

  // ---- precomputed staging pointers (advance by 64 elems per K-iter) ----
  const unsigned short* ga[4];
  const unsigned short* gb[4];
  void* la[4];
  void* lb[4];
  #pragma unroll
  for (int i = 0; i < 4; ++i) {
    const int c   = wave * 4 + i;
    const int row = c * 8 + l8;
    ga[i] = Ag + (long long)row * lda + srcCb * 8;
    gb[i] = Bg + (long long)row * ldb + srcCb * 8;
    la[i] = &smA[c * 512];
    lb[i] = &smB[c * 512];
  }

  // ---- precomputed frag-read bases (K-invariant; reads use +f*1024 elems) ----
  const int sxor = l15 & 7;
  const short* baseA[2];
  const short* baseB[2];
  #pragma unroll
  for (int kk = 0; kk < 2; ++kk) {
    baseA[kk] = &smA[(wm * 64 + l15) * 64 + ((kk * 4 + l4q) ^ sxor) * 8];
    baseB[kk] = &smB[(wn * 64 + l15) * 64 + ((kk * 4 + l4q) ^ sxor) * 8];
  }

  v4f acc[4][4] = {};

  for (int it = K >> 6; it > 0; --it) {
    #pragma unroll
    for (int i = 0; i < 4; ++i) {
      gload_lds16(ga[i], la[i]);
      gload_lds16(gb[i], lb[i]);
      ga[i] += 64;
      gb[i] += 64;
    }
    __syncthreads();
    #pragma unroll
    for (int kk = 0; kk < 2; ++kk) {
      v8s af[4], bf[4];
      #pragma unroll
      for (int f = 0; f < 4; ++f) {
        af[f] = *(const v8s*)(baseA[kk] + f * 1024);
        bf[f] = *(const v8s*)(baseB[kk] + f * 1024);
      }
      #pragma unroll
      for (int fm = 0; fm < 4; ++fm)
        #pragma unroll
        for (int fn = 0; fn < 4; ++fn)
          acc[fm][fn] = __builtin_amdgcn_mfma_f32_16x16x32_bf16(af[fm], bf[fn], acc[fm][fn], 0, 0, 0);
    }
    __syncthreads();
  }

  // ---- epilogue: C/D layout col=lane&15, row=(lane>>4)*4+reg ----
  const int row0 = tileM + wm * 64 + (lane >> 4) * 4;
  const int col0 = tileN + wn * 64 + l15;

  #pragma unroll
  for (int fm = 0; fm < 4; ++fm) {
    #pragma unroll
    for (int fn = 0; fn < 4; ++fn) {
      const int col = col0 + fn * 16;
      if (MODE == EPI_QKV) {
        const float bb = bias[col];
        if (tileN >= 2048) {
          // V^T: d=col-2048, batch=row>>11, s=row&2047 (4 consecutive)
          const int rowb = row0 + fm * 16;
          const int d = col - 2048;
          const int b = rowb >> 11;
          const int s0 = rowb & 2047;
          ushort4 w;
          w.x = f32_to_bf16(acc[fm][fn][0] + bb);
          w.y = f32_to_bf16(acc[fm][fn][1] + bb);
          w.z = f32_to_bf16(acc[fm][fn][2] + bb);
          w.w = f32_to_bf16(acc[fm][fn][3] + bb);
          *(ushort4*)&vt[((long long)b * 1024 + d) * 2048 + s0] = w;
        } else {
          unsigned short* dst = (tileN < 1024) ? qb : kb;
          const int colr = col & 1023;
          #pragma unroll
          for (int r = 0; r < 4; ++r) {
            const int row = row0 + fm * 16 + r;
            dst[(long long)row * 1024 + colr] = f32_to_bf16(acc[fm][fn][r] + bb);
          }
        }
      } else {
        #pragma unroll
        for (int r = 0; r < 4; ++r) {
          const int row = row0 + fm * 16 + r;
          const float v = acc[fm][fn][r];
          if (MODE == EPI_BF16_SCALE) {
            unsigned short* C = (unsigned short*)Cout + (long long)bz * strideC;
            C[(long long)row * ldc + col] = f32_to_bf16(v * scale);
          } else if (MODE == EPI_F32_BIAS) {
            float* C = (float*)Cout + (long long)bz * strideC;
            C[(long long)row * ldc + col] = v + bias[col];
          } else {
            unsigned short* C = (unsigned short*)Cout + (long long)bz * strideC;
            C[(long long)row * ldc + col] = f32_to_bf16(v);
          }
        }
      }
    }
  }
}

// ---------------------------------------------------------------------------
__global__ __launch_bounds__(256)
void cvt_f32_bf16_kernel(const float* __restrict__ in, unsigned short* __restrict__ out,
                         long long n)
{
  const long long i = ((long long)blockIdx.x * 256 + threadIdx.x) * 4;
  if (i >= n) return;
  const float4 v = *(const float4*)(in + i);
  typedef __attribute__((ext_vector_type(4))) unsigned short v4us;
  v4us o;
  o.x = f32_to_bf16(v.x); o.y = f32_to_bf16(v.y);
  o.z = f32_to_bf16(v.z); o.w = f32_to_bf16(v.w);
  *(v4us*)(out + i) = o;
}

__global__ __launch_bounds__(256)
void transpose_f32_bf16_kernel(const float* __restrict__ in, unsigned short* __restrict__ out,
                               int R, int C)   // in [R][C] f32 -> out [C][R] bf16
{
  __shared__ float t[32][33];
  const int c0 = blockIdx.x * 32, r0 = blockIdx.y * 32;
  const int tx = threadIdx.x, ty = threadIdx.y;
  for (int i = ty; i < 32; i += 8)
    t[i][tx] = in[(long long)(r0 + i) * C + (c0 + tx)];
  __syncthreads();
  for (int i = ty; i < 32; i += 8)
    out[(long long)(c0 + i) * R + (r0 + tx)] = f32_to_bf16(t[tx][i]);
}

// one WAVE per row: probs = softmax(bf16_scores + sw_f32). 4 rows/block,
// pure shuffle reduction, vectorized sw (float4) and score (v8s) loads.
__global__ __launch_bounds__(256)
void softmax_rows_bf16(const unsigned short* __restrict__ scores,
                       const float* __restrict__ sw,
                       unsigned short* __restrict__ probs)
{
  const int wid  = threadIdx.x >> 6;
  const int lane = threadIdx.x & 63;
  const long long row = (long long)blockIdx.x * 4 + wid;
  const unsigned short* src = scores + row * 2048;
  const float* swr = sw + row * 2048;
  unsigned short* dst = probs + row * 2048;

  float v[32];
  #pragma unroll
  for (int c = 0; c < 4; ++c) {
    const v8s in = *(const v8s*)(src + c * 512 + lane * 8);
    const float4 s0 = *(const float4*)(swr + c * 512 + lane * 8);
    const float4 s1 = *(const float4*)(swr + c * 512 + lane * 8 + 4);
    v[c * 8 + 0] = bf16_to_f32((unsigned short)in[0]) + s0.x;
    v[c * 8 + 1] = bf16_to_f32((unsigned short)in[1]) + s0.y;
    v[c * 8 + 2] = bf16_to_f32((unsigned short)in[2]) + s0.z;
    v[c * 8 + 3] = bf16_to_f32((unsigned short)in[3]) + s0.w;
    v[c * 8 + 4] = bf16_to_f32((unsigned short)in[4]) + s1.x;
    v[c * 8 + 5] = bf16_to_f32((unsigned short)in[5]) + s1.y;
    v[c * 8 + 6] = bf16_to_f32((unsigned short)in[6]) + s1.z;
    v[c * 8 + 7] = bf16_to_f32((unsigned short)in[7]) + s1.w;
  }

  float m = v[0];
  #pragma unroll
  for (int j = 1; j < 32; ++j) m = fmaxf(m, v[j]);
  #pragma unroll
  for (int o = 32; o; o >>= 1) m = fmaxf(m, __shfl_xor(m, o));

  float s = 0.f;
  #pragma unroll
  for (int j = 0; j < 32; ++j) { v[j] = __expf(v[j] - m); s += v[j]; }
  #pragma unroll
  for (int o = 32; o; o >>= 1) s += __shfl_xor(s, o);
  const float inv = 1.0f / s;

  #pragma unroll
  for (int c = 0; c < 4; ++c) {
    v8s o8;
    #pragma unroll
    for (int j = 0; j < 8; ++j) o8[j] = (short)f32_to_bf16(v[c * 8 + j] * inv);
    *(v8s*)(dst + c * 512 + lane * 8) = o8;
  }
}

// ---------------------------------------------------------------------------
extern "C" void kernel_launch(void* const* d_in, const int* in_sizes, int n_in,
                              void* d_out, int out_size, void* d_ws, size_t ws_size,
                              hipStream_t stream) {
  (void)in_sizes; (void)n_in; (void)out_size; (void)ws_size;
  const float* x   = (const float*)d_in[0];
  const float* sw  = (const float*)d_in[1];
  const float* W_c = (const float*)d_in[2];
  const float* b_c = (const float*)d_in[3];
  const float* W_p = (const float*)d_in[4];
  const float* b_p = (const float*)d_in[5];
  float* out = (float*)d_out;

  const int Bb = 4, S = 2048, H = 1024, Ha = 1024, P = 1024;
  const int M = Bb * S;                              // 8192
  char* ws = (char*)d_ws;
  const long long MB = 1024LL * 1024LL;
  // ws layout (120 MB), time-sliced overlap in [0,32MB):
  //   x_bf [0,16) steps 1-4 | scores [0,32) steps 5-6 | ctx [0,16) steps 7-8
  unsigned short* scores = (unsigned short*)(ws + 0);         // 32 MB bf16 [B*S][S]
  unsigned short* x_bf   = (unsigned short*)(ws + 0);         // 16 MB
  unsigned short* ctx    = (unsigned short*)(ws + 0);         // 16 MB
  unsigned short* probs  = (unsigned short*)(ws + 32 * MB);   // 32 MB
  unsigned short* qbuf   = (unsigned short*)(ws + 64 * MB);   // 16 MB [8192][1024]
  unsigned short* kbuf   = (unsigned short*)(ws + 80 * MB);   // 16 MB [8192][1024]
  unsigned short* Vt     = (unsigned short*)(ws + 96 * MB);   // 16 MB [4][1024][2048]
  unsigned short* Wc_t   = (unsigned short*)(ws + 112 * MB);  // 6 MB  [3072][1024]
  unsigned short* Wp_t   = (unsigned short*)(ws + 118 * MB);  // 2 MB  [1024][1024]

  const dim3 tb(32, 8);

  // 1) x -> bf16
  cvt_f32_bf16_kernel<<<(unsigned)((long long)M * H / 4 / 256), 256, 0, stream>>>(
      x, x_bf, (long long)M * H);
  // 2,3) W_c^T, W_p^T (f32 -> bf16)
  transpose_f32_bf16_kernel<<<dim3(3 * Ha / 32, H / 32), tb, 0, stream>>>(W_c, Wc_t, H, 3 * Ha);
  transpose_f32_bf16_kernel<<<dim3(P / 32, Ha / 32), tb, 0, stream>>>(W_p, Wp_t, Ha, P);
  // 4) QKV: Q -> qbuf dense, K -> kbuf dense, V -> Vt (transposed), all +b_c
  gemm_nt<EPI_QKV><<<dim3(3 * Ha / 128, M / 128, 1), 256, 0, stream>>>(
      x_bf, 0, H, Wc_t, 0, H, nullptr, 0, 0, b_c, 0.f, H, qbuf, kbuf, Vt);
  // 5) scores = bf16((Q @ K^T) * rsqrt(1024))   (+sw deferred to softmax)
  gemm_nt<EPI_BF16_SCALE><<<dim3(S / 128, S / 128, Bb), 256, 0, stream>>>(
      qbuf, (long long)S * Ha, Ha, kbuf, (long long)S * Ha, Ha,
      scores, (long long)S * S, S, nullptr, 0.03125f, Ha,
      nullptr, nullptr, nullptr);
  // 6) probs = softmax(scores + sw)  (wave per row)
  softmax_rows_bf16<<<Bb * S / 4, 256, 0, stream>>>(scores, sw, probs);
  // 7) ctx = probs @ V   (bf16 out)
  gemm_nt<EPI_BF16><<<dim3(Ha / 128, S / 128, Bb), 256, 0, stream>>>(
      probs, (long long)S * S, S, Vt, (long long)Ha * S, S,
      ctx, (long long)S * Ha, Ha, nullptr, 0.f, S,
      nullptr, nullptr, nullptr);
  // 8) out = ctx @ W_p + b_p   (fp32 out)
  gemm_nt<EPI_F32_BIAS><<<dim3(P / 128, M / 128, 1), 256, 0, stream>>>(
      ctx, 0, Ha, Wp_t, 0, Ha, out, 0, P, b_p, 0.f, Ha,
      nullptr, nullptr, nullptr);
}